// Round 2
// baseline (464.638 us; speedup 1.0000x reference)
//
#include <hip/hip_runtime.h>
#include <math.h>

#define NQ 14
#define NP 140
#define NT 1024

typedef float2 f2;

__device__ __forceinline__ float sigmoid2pi(float x) {
    return 6.28318530717958647692f / (1.0f + __expf(-x));
}

__device__ __forceinline__ f2 cmulf(f2 a, f2 b) {
    return make_float2(a.x * b.x - a.y * b.y, a.x * b.y + a.y * b.x);
}

// ca*m + cb*o (complex)
__device__ __forceinline__ f2 comb(f2 ca, f2 m, f2 cb, f2 o) {
    return make_float2(ca.x * m.x - ca.y * m.y + cb.x * o.x - cb.y * o.y,
                       ca.x * m.y + ca.y * m.x + cb.x * o.y + cb.y * o.x);
}

// RX half: n = ch*m - i*sh*o
__device__ __forceinline__ f2 rxmix(float ch, float sh, f2 m, f2 o) {
    return make_float2(ch * m.x + sh * o.y, ch * m.y - sh * o.x);
}

// ---------------- fused RZ*RY*RX single-qubit gate ----------------
template<int Q>
__device__ __forceinline__ void gate1q(f2* st, f2 (*ex)[NT], int tid, const float* g) {
    f2 u00 = make_float2(g[0], g[1]), u01 = make_float2(g[2], g[3]);
    f2 u10 = make_float2(g[4], g[5]), u11 = make_float2(g[6], g[7]);
    constexpr int B = 13 - Q;
    if constexpr (B < 4) {                       // register-local pairs
        constexpr int M = 1 << B;
        #pragma unroll
        for (int p = 0; p < 8; ++p) {
            int i0 = ((p >> B) << (B + 1)) | (p & (M - 1));
            int i1 = i0 | M;
            f2 a0 = st[i0], a1 = st[i1];
            st[i0] = comb(u00, a0, u01, a1);
            st[i1] = comb(u10, a0, u11, a1);
        }
    } else if constexpr (B < 10) {               // lane-bit: shuffle exchange
        constexpr int LM = 1 << (B - 4);
        int bit = (tid >> (B - 4)) & 1;
        f2 ca = bit ? u11 : u00;
        f2 cb = bit ? u10 : u01;
        #pragma unroll
        for (int i = 0; i < 16; ++i) {
            f2 o;
            o.x = __shfl_xor(st[i].x, LM);
            o.y = __shfl_xor(st[i].y, LM);
            st[i] = comb(ca, st[i], cb, o);
        }
    } else {                                     // wave-bit: LDS exchange
        constexpr int TM = 1 << (B - 4);
        int bit = (tid >> (B - 4)) & 1;
        f2 ca = bit ? u11 : u00;
        f2 cb = bit ? u10 : u01;
        int ptid = tid ^ TM;
        __syncthreads();
        #pragma unroll
        for (int i = 0; i < 16; ++i) ex[i][tid] = st[i];
        __syncthreads();
        #pragma unroll
        for (int i = 0; i < 16; ++i) {
            f2 o = ex[i][ptid];
            st[i] = comb(ca, st[i], cb, o);
        }
    }
}

// ---------------- controlled-RX ----------------
template<int C, int T>
__device__ __forceinline__ void gatecrx(f2* st, f2 (*ex)[NT], int tid, float ch, float sh) {
    constexpr int TB = 13 - T, CB = 13 - C;
    if constexpr (TB < 4) {                      // target register-local
        constexpr int M = 1 << TB;
        if constexpr (CB < 4) {                  // ctrl local: compile-time subset
            #pragma unroll
            for (int p = 0; p < 8; ++p) {
                int i0 = ((p >> TB) << (TB + 1)) | (p & (M - 1));
                int i1 = i0 | M;
                if ((i0 >> CB) & 1) {
                    f2 a0 = st[i0], a1 = st[i1];
                    st[i0] = rxmix(ch, sh, a0, a1);
                    st[i1] = rxmix(ch, sh, a1, a0);
                }
            }
        } else {                                 // ctrl lane/wave: uniform predicate
            bool sel = (tid >> (CB - 4)) & 1;
            if (sel) {
                #pragma unroll
                for (int p = 0; p < 8; ++p) {
                    int i0 = ((p >> TB) << (TB + 1)) | (p & (M - 1));
                    int i1 = i0 | M;
                    f2 a0 = st[i0], a1 = st[i1];
                    st[i0] = rxmix(ch, sh, a0, a1);
                    st[i1] = rxmix(ch, sh, a1, a0);
                }
            }
        }
    } else if constexpr (TB < 10) {              // target lane-bit
        constexpr int LM = 1 << (TB - 4);
        if constexpr (CB < 4) {                  // ctrl local: shuffle only needed amps
            #pragma unroll
            for (int i = 0; i < 16; ++i) {
                if ((i >> CB) & 1) {
                    f2 o;
                    o.x = __shfl_xor(st[i].x, LM);
                    o.y = __shfl_xor(st[i].y, LM);
                    st[i] = rxmix(ch, sh, st[i], o);
                }
            }
        } else if constexpr (CB >= 10) {         // ctrl wave: wave-uniform branch
            bool sel = (tid >> (CB - 4)) & 1;
            if (sel) {
                #pragma unroll
                for (int i = 0; i < 16; ++i) {
                    f2 o;
                    o.x = __shfl_xor(st[i].x, LM);
                    o.y = __shfl_xor(st[i].y, LM);
                    st[i] = rxmix(ch, sh, st[i], o);
                }
            }
        } else {                                 // ctrl lane: divergent -> select
            bool sel = (tid >> (CB - 4)) & 1;
            #pragma unroll
            for (int i = 0; i < 16; ++i) {
                f2 o;
                o.x = __shfl_xor(st[i].x, LM);
                o.y = __shfl_xor(st[i].y, LM);
                f2 n = rxmix(ch, sh, st[i], o);
                st[i] = sel ? n : st[i];
            }
        }
    } else {                                     // target wave-bit: LDS exchange
        constexpr int TM = 1 << (TB - 4);
        int ptid = tid ^ TM;
        bool act = true;
        if constexpr (CB >= 4) act = (tid >> (CB - 4)) & 1;
        __syncthreads();
        if (act) {
            #pragma unroll
            for (int i = 0; i < 16; ++i) {
                if constexpr (CB < 4) { if (!((i >> CB) & 1)) continue; }
                ex[i][tid] = st[i];
            }
        }
        __syncthreads();
        if (act) {
            #pragma unroll
            for (int i = 0; i < 16; ++i) {
                if constexpr (CB < 4) { if (!((i >> CB) & 1)) continue; }
                f2 o = ex[i][ptid];
                st[i] = rxmix(ch, sh, st[i], o);
            }
        }
    }
}

// ---------------- measurement of one wire ----------------
template<int W>
__device__ __forceinline__ void measure_wire(const f2* st, f2 (*ex)[NT], int tid,
                                             float red[14][16][3]) {
    constexpr int B = 13 - W;
    float sx = 0.f, sy = 0.f, sz = 0.f;
    if constexpr (B < 4) {                       // local pairs
        constexpr int M = 1 << B;
        #pragma unroll
        for (int p = 0; p < 8; ++p) {
            int i0 = ((p >> B) << (B + 1)) | (p & (M - 1));
            int i1 = i0 | M;
            f2 a0 = st[i0], a1 = st[i1];
            sx += a0.x * a1.x + a0.y * a1.y;
            sy += a0.x * a1.y - a0.y * a1.x;
            sz += (a0.x * a0.x + a0.y * a0.y) - (a1.x * a1.x + a1.y * a1.y);
        }
        sx *= 2.f; sy *= 2.f;                    // local pairs counted once
    } else {                                     // both-sides accumulation
        int bit = (tid >> (B - 4)) & 1;
        float sg = bit ? -1.f : 1.f;
        #pragma unroll
        for (int i = 0; i < 16; ++i) {
            f2 m = st[i], o;
            if constexpr (B < 10) {
                o.x = __shfl_xor(m.x, 1 << (B - 4));
                o.y = __shfl_xor(m.y, 1 << (B - 4));
            } else {
                o = ex[i][tid ^ (1 << (B - 4))];
            }
            sx += m.x * o.x + m.y * o.y;
            sy += sg * (m.x * o.y - m.y * o.x);
            sz += sg * (m.x * m.x + m.y * m.y);
        }
    }
    // wave-level reduce
    #pragma unroll
    for (int off = 32; off > 0; off >>= 1) {
        sx += __shfl_down(sx, off);
        sy += __shfl_down(sy, off);
        sz += __shfl_down(sz, off);
    }
    if ((tid & 63) == 0) {
        int wv = tid >> 6;
        red[W][wv][0] = sx; red[W][wv][1] = sy; red[W][wv][2] = sz;
    }
}

__global__ __launch_bounds__(NT)
void qfe_kernel(const float* __restrict__ params,
                const float* __restrict__ base,
                float* __restrict__ out)
{
    __shared__ f2 ex[16][NT];            // 128 KB exchange buffer
    __shared__ float v1[14][4];          // layer-1 1q columns (u00, u10)
    __shared__ float g1[14][8];          // layer-2 fused 1q matrices
    __shared__ float csh[56][2];         // CRX (cos, sin) half-angle, exec order
    __shared__ float red[14][16][3];     // per-wave measurement partials

    const int b = blockIdx.x;
    const int tid = threadIdx.x;

    // ------- precompute all gate data (divergent, one-time) -------
    if (tid < 14) {                      // layer-1 columns
        int q = tid, a = 3 * q;
        float t1 = sigmoid2pi(params[b * NP + a] + base[a]);
        float t2 = sigmoid2pi(params[b * NP + a + 1] + base[a + 1]);
        float t3 = sigmoid2pi(params[b * NP + a + 2] + base[a + 2]);
        float s1, c1, s2, c2, s3, c3;
        __sincosf(0.5f * t1, &s1, &c1);
        __sincosf(0.5f * t2, &s2, &c2);
        __sincosf(0.5f * t3, &s3, &c3);
        f2 m00 = make_float2(c2 * c1, s2 * s1);
        f2 m10 = make_float2(s2 * c1, -c2 * s1);
        f2 em = make_float2(c3, -s3), ep = make_float2(c3, s3);
        f2 u00 = cmulf(em, m00), u10 = cmulf(ep, m10);
        v1[q][0] = u00.x; v1[q][1] = u00.y; v1[q][2] = u10.x; v1[q][3] = u10.y;
    } else if (tid >= 64 && tid < 78) {  // layer-2 fused matrices
        int q = tid - 64, a = 70 + 3 * q;
        float t1 = sigmoid2pi(params[b * NP + a] + base[a]);
        float t2 = sigmoid2pi(params[b * NP + a + 1] + base[a + 1]);
        float t3 = sigmoid2pi(params[b * NP + a + 2] + base[a + 2]);
        float s1, c1, s2, c2, s3, c3;
        __sincosf(0.5f * t1, &s1, &c1);
        __sincosf(0.5f * t2, &s2, &c2);
        __sincosf(0.5f * t3, &s3, &c3);
        f2 m00 = make_float2(c2 * c1, s2 * s1);
        f2 m01 = make_float2(-s2 * c1, -c2 * s1);
        f2 m10 = make_float2(s2 * c1, -c2 * s1);
        f2 m11 = make_float2(c2 * c1, -s2 * s1);
        f2 em = make_float2(c3, -s3), ep = make_float2(c3, s3);
        f2 u00 = cmulf(em, m00), u01 = cmulf(em, m01);
        f2 u10 = cmulf(ep, m10), u11 = cmulf(ep, m11);
        g1[q][0] = u00.x; g1[q][1] = u00.y; g1[q][2] = u01.x; g1[q][3] = u01.y;
        g1[q][4] = u10.x; g1[q][5] = u10.y; g1[q][6] = u11.x; g1[q][7] = u11.y;
    } else if (tid >= 128 && tid < 184) { // CRX cos/sin in execution order
        int s = tid - 128;
        int layer = s / 28, k = s % 28;
        int aidx = layer * 70 + (k < 14 ? 42 + k : 56 + (k - 14));
        float th = sigmoid2pi(params[b * NP + aidx] + base[aidx]);
        float sh, ch;
        __sincosf(0.5f * th, &sh, &ch);
        csh[s][0] = ch; csh[s][1] = sh;
    }
    __syncthreads();

    // ------- initial state: product of layer-1 1q columns -------
    f2 F = make_float2(1.f, 0.f);
    #pragma unroll
    for (int q = 0; q < 10; ++q) {
        int bit = (tid >> (9 - q)) & 1;
        f2 v = make_float2(v1[q][2 * bit], v1[q][2 * bit + 1]);
        F = cmulf(F, v);
    }
    f2 st[16];
    {
        f2 t2a[2], t4a[4], t8a[8];
        #pragma unroll
        for (int a = 0; a < 2; ++a)
            t2a[a] = cmulf(F, make_float2(v1[10][2 * a], v1[10][2 * a + 1]));
        #pragma unroll
        for (int a = 0; a < 4; ++a)
            t4a[a] = cmulf(t2a[a >> 1], make_float2(v1[11][2 * (a & 1)], v1[11][2 * (a & 1) + 1]));
        #pragma unroll
        for (int a = 0; a < 8; ++a)
            t8a[a] = cmulf(t4a[a >> 1], make_float2(v1[12][2 * (a & 1)], v1[12][2 * (a & 1) + 1]));
        #pragma unroll
        for (int i = 0; i < 16; ++i)
            st[i] = cmulf(t8a[i >> 1], make_float2(v1[13][2 * (i & 1)], v1[13][2 * (i & 1) + 1]));
    }

    // ------- gate sequence -------
#define CRXF_(L, i, j) gatecrx<i, j>(st, ex, tid, csh[(L)*28 + (i)][0], csh[(L)*28 + (i)][1]);
#define CRXB_(L, i, j) gatecrx<i, j>(st, ex, tid, csh[(L)*28 + 27 - (i)][0], csh[(L)*28 + 27 - (i)][1]);
#define FWD_RING(L) \
    CRXF_(L,0,1) CRXF_(L,1,2) CRXF_(L,2,3) CRXF_(L,3,4) CRXF_(L,4,5) CRXF_(L,5,6) CRXF_(L,6,7) \
    CRXF_(L,7,8) CRXF_(L,8,9) CRXF_(L,9,10) CRXF_(L,10,11) CRXF_(L,11,12) CRXF_(L,12,13) CRXF_(L,13,0)
#define BWD_RING(L) \
    CRXB_(L,13,12) CRXB_(L,12,11) CRXB_(L,11,10) CRXB_(L,10,9) CRXB_(L,9,8) CRXB_(L,8,7) CRXB_(L,7,6) \
    CRXB_(L,6,5) CRXB_(L,5,4) CRXB_(L,4,3) CRXB_(L,3,2) CRXB_(L,2,1) CRXB_(L,1,0) CRXB_(L,0,13)
#define G1Q(q) gate1q<q>(st, ex, tid, g1[q]);

    // layer 1 (1q section folded into initial state)
    FWD_RING(0)
    BWD_RING(0)
    // layer 2
    G1Q(0) G1Q(1) G1Q(2) G1Q(3) G1Q(4) G1Q(5) G1Q(6)
    G1Q(7) G1Q(8) G1Q(9) G1Q(10) G1Q(11) G1Q(12) G1Q(13)
    FWD_RING(1)
    BWD_RING(1)

    // ------- dump state for wave-bit measurement wires -------
    __syncthreads();
    #pragma unroll
    for (int i = 0; i < 16; ++i) ex[i][tid] = st[i];
    __syncthreads();

#define MEAS(W) measure_wire<W>(st, ex, tid, red);
    MEAS(0) MEAS(1) MEAS(2) MEAS(3) MEAS(4) MEAS(5) MEAS(6)
    MEAS(7) MEAS(8) MEAS(9) MEAS(10) MEAS(11) MEAS(12) MEAS(13)

    __syncthreads();
    if (tid < 42) {
        int comp = tid / 14, w = tid % 14;
        float s = 0.f;
        #pragma unroll
        for (int k = 0; k < 16; ++k) s += red[w][k][comp];
        out[b * 42 + comp * 14 + w] = s;
    }
}

extern "C" void kernel_launch(void* const* d_in, const int* in_sizes, int n_in,
                              void* d_out, int out_size, void* d_ws, size_t ws_size,
                              hipStream_t stream) {
    const float* params = (const float*)d_in[0];   // [B, 140]
    const float* base   = (const float*)d_in[1];   // [140]
    float* out = (float*)d_out;                    // [B, 42]
    const int B = in_sizes[0] / NP;
    qfe_kernel<<<B, NT, 0, stream>>>(params, base, out);
}

// Round 3
// 111.123 us; speedup vs baseline: 4.1813x; 4.1813x over previous
//
#include <hip/hip_runtime.h>
#include <math.h>

#define NQ 14
#define NP 140
#define NT 1024

typedef float2 f2;

__device__ __forceinline__ float sigmoid2pi(float x) {
    return 6.28318530717958647692f / (1.0f + __expf(-x));
}

__device__ __forceinline__ f2 cmulf(f2 a, f2 b) {
    return make_float2(a.x * b.x - a.y * b.y, a.x * b.y + a.y * b.x);
}

// ca*m + cb*o (complex)
__device__ __forceinline__ f2 comb(f2 ca, f2 m, f2 cb, f2 o) {
    return make_float2(ca.x * m.x - ca.y * m.y + cb.x * o.x - cb.y * o.y,
                       ca.x * m.y + ca.y * m.x + cb.x * o.y + cb.y * o.x);
}

// RX half: n = ch*m - i*sh*o
__device__ __forceinline__ f2 rxmix(float ch, float sh, f2 m, f2 o) {
    return make_float2(ch * m.x + sh * o.y, ch * m.y - sh * o.x);
}

// ---------------- fused RZ*RY*RX single-qubit gate ----------------
template<int Q>
__device__ __forceinline__ void gate1q(f2 (&st)[16], f2 (*ex)[NT], int tid, const float* g) {
    f2 u00 = make_float2(g[0], g[1]), u01 = make_float2(g[2], g[3]);
    f2 u10 = make_float2(g[4], g[5]), u11 = make_float2(g[6], g[7]);
    constexpr int B = 13 - Q;
    if constexpr (B < 4) {                       // register-local pairs
        constexpr int M = 1 << B;
        #pragma unroll
        for (int p = 0; p < 8; ++p) {
            int i0 = ((p >> B) << (B + 1)) | (p & (M - 1));
            int i1 = i0 | M;
            f2 a0 = st[i0], a1 = st[i1];
            st[i0] = comb(u00, a0, u01, a1);
            st[i1] = comb(u10, a0, u11, a1);
        }
    } else if constexpr (B < 10) {               // lane-bit: shuffle exchange
        constexpr int LM = 1 << (B - 4);
        int bit = (tid >> (B - 4)) & 1;
        f2 ca = bit ? u11 : u00;
        f2 cb = bit ? u10 : u01;
        #pragma unroll
        for (int i = 0; i < 16; ++i) {
            f2 o;
            o.x = __shfl_xor(st[i].x, LM);
            o.y = __shfl_xor(st[i].y, LM);
            st[i] = comb(ca, st[i], cb, o);
        }
    } else {                                     // wave-bit: LDS exchange
        constexpr int TM = 1 << (B - 4);
        int bit = (tid >> (B - 4)) & 1;
        f2 ca = bit ? u11 : u00;
        f2 cb = bit ? u10 : u01;
        int ptid = tid ^ TM;
        __syncthreads();
        #pragma unroll
        for (int i = 0; i < 16; ++i) ex[i][tid] = st[i];
        __syncthreads();
        #pragma unroll
        for (int i = 0; i < 16; ++i) {
            f2 o = ex[i][ptid];
            st[i] = comb(ca, st[i], cb, o);
        }
    }
}

// ---------------- controlled-RX ----------------
template<int C, int T>
__device__ __forceinline__ void gatecrx(f2 (&st)[16], f2 (*ex)[NT], int tid, float ch, float sh) {
    constexpr int TB = 13 - T, CB = 13 - C;
    if constexpr (TB < 4) {                      // target register-local
        constexpr int M = 1 << TB;
        if constexpr (CB < 4) {                  // ctrl local: compile-time subset
            #pragma unroll
            for (int p = 0; p < 8; ++p) {
                int i0 = ((p >> TB) << (TB + 1)) | (p & (M - 1));
                int i1 = i0 | M;
                if ((i0 >> CB) & 1) {
                    f2 a0 = st[i0], a1 = st[i1];
                    st[i0] = rxmix(ch, sh, a0, a1);
                    st[i1] = rxmix(ch, sh, a1, a0);
                }
            }
        } else {                                 // ctrl lane/wave: uniform predicate
            bool sel = (tid >> (CB - 4)) & 1;
            if (sel) {
                #pragma unroll
                for (int p = 0; p < 8; ++p) {
                    int i0 = ((p >> TB) << (TB + 1)) | (p & (M - 1));
                    int i1 = i0 | M;
                    f2 a0 = st[i0], a1 = st[i1];
                    st[i0] = rxmix(ch, sh, a0, a1);
                    st[i1] = rxmix(ch, sh, a1, a0);
                }
            }
        }
    } else if constexpr (TB < 10) {              // target lane-bit
        constexpr int LM = 1 << (TB - 4);
        if constexpr (CB < 4) {                  // ctrl local: shuffle only needed amps
            #pragma unroll
            for (int i = 0; i < 16; ++i) {
                if ((i >> CB) & 1) {
                    f2 o;
                    o.x = __shfl_xor(st[i].x, LM);
                    o.y = __shfl_xor(st[i].y, LM);
                    st[i] = rxmix(ch, sh, st[i], o);
                }
            }
        } else if constexpr (CB >= 10) {         // ctrl wave: wave-uniform branch
            bool sel = (tid >> (CB - 4)) & 1;
            if (sel) {
                #pragma unroll
                for (int i = 0; i < 16; ++i) {
                    f2 o;
                    o.x = __shfl_xor(st[i].x, LM);
                    o.y = __shfl_xor(st[i].y, LM);
                    st[i] = rxmix(ch, sh, st[i], o);
                }
            }
        } else {                                 // ctrl lane: divergent -> select
            bool sel = (tid >> (CB - 4)) & 1;
            #pragma unroll
            for (int i = 0; i < 16; ++i) {
                f2 o;
                o.x = __shfl_xor(st[i].x, LM);
                o.y = __shfl_xor(st[i].y, LM);
                f2 n = rxmix(ch, sh, st[i], o);
                st[i] = sel ? n : st[i];
            }
        }
    } else {                                     // target wave-bit: LDS exchange
        constexpr int TM = 1 << (TB - 4);
        int ptid = tid ^ TM;
        bool act = true;
        if constexpr (CB >= 4) act = (tid >> (CB - 4)) & 1;
        __syncthreads();
        if (act) {
            #pragma unroll
            for (int i = 0; i < 16; ++i) {
                if constexpr (CB < 4) { if (!((i >> CB) & 1)) continue; }
                ex[i][tid] = st[i];
            }
        }
        __syncthreads();
        if (act) {
            #pragma unroll
            for (int i = 0; i < 16; ++i) {
                if constexpr (CB < 4) { if (!((i >> CB) & 1)) continue; }
                f2 o = ex[i][ptid];
                st[i] = rxmix(ch, sh, st[i], o);
            }
        }
    }
}

// ---------------- measurement of one wire ----------------
template<int W>
__device__ __forceinline__ void measure_wire(const f2 (&st)[16], f2 (*ex)[NT], int tid,
                                             float red[14][16][3]) {
    constexpr int B = 13 - W;
    float sx = 0.f, sy = 0.f, sz = 0.f;
    if constexpr (B < 4) {                       // local pairs
        constexpr int M = 1 << B;
        #pragma unroll
        for (int p = 0; p < 8; ++p) {
            int i0 = ((p >> B) << (B + 1)) | (p & (M - 1));
            int i1 = i0 | M;
            f2 a0 = st[i0], a1 = st[i1];
            sx += a0.x * a1.x + a0.y * a1.y;
            sy += a0.x * a1.y - a0.y * a1.x;
            sz += (a0.x * a0.x + a0.y * a0.y) - (a1.x * a1.x + a1.y * a1.y);
        }
        sx *= 2.f; sy *= 2.f;                    // local pairs counted once
    } else {                                     // both-sides accumulation
        int bit = (tid >> (B - 4)) & 1;
        float sg = bit ? -1.f : 1.f;
        #pragma unroll
        for (int i = 0; i < 16; ++i) {
            f2 m = st[i], o;
            if constexpr (B < 10) {
                o.x = __shfl_xor(m.x, 1 << (B - 4));
                o.y = __shfl_xor(m.y, 1 << (B - 4));
            } else {
                o = ex[i][tid ^ (1 << (B - 4))];
            }
            sx += m.x * o.x + m.y * o.y;
            sy += sg * (m.x * o.y - m.y * o.x);
            sz += sg * (m.x * m.x + m.y * m.y);
        }
    }
    // wave-level reduce
    #pragma unroll
    for (int off = 32; off > 0; off >>= 1) {
        sx += __shfl_down(sx, off);
        sy += __shfl_down(sy, off);
        sz += __shfl_down(sz, off);
    }
    if ((tid & 63) == 0) {
        int wv = tid >> 6;
        red[W][wv][0] = sx; red[W][wv][1] = sy; red[W][wv][2] = sz;
    }
}

__global__ __launch_bounds__(NT, 4)   // 4 waves/SIMD = 16 waves/CU = 1 block/CU -> 128-VGPR cap
void qfe_kernel(const float* __restrict__ params,
                const float* __restrict__ base,
                float* __restrict__ out)
{
    __shared__ f2 ex[16][NT];            // 128 KB exchange buffer
    __shared__ float v1[14][4];          // layer-1 1q columns (u00, u10)
    __shared__ float g1[14][8];          // layer-2 fused 1q matrices
    __shared__ float csh[56][2];         // CRX (cos, sin) half-angle, exec order
    __shared__ float red[14][16][3];     // per-wave measurement partials

    const int b = blockIdx.x;
    const int tid = threadIdx.x;

    // ------- precompute all gate data (divergent, one-time) -------
    if (tid < 14) {                      // layer-1 columns
        int q = tid, a = 3 * q;
        float t1 = sigmoid2pi(params[b * NP + a] + base[a]);
        float t2 = sigmoid2pi(params[b * NP + a + 1] + base[a + 1]);
        float t3 = sigmoid2pi(params[b * NP + a + 2] + base[a + 2]);
        float s1, c1, s2, c2, s3, c3;
        __sincosf(0.5f * t1, &s1, &c1);
        __sincosf(0.5f * t2, &s2, &c2);
        __sincosf(0.5f * t3, &s3, &c3);
        f2 m00 = make_float2(c2 * c1, s2 * s1);
        f2 m10 = make_float2(s2 * c1, -c2 * s1);
        f2 em = make_float2(c3, -s3), ep = make_float2(c3, s3);
        f2 u00 = cmulf(em, m00), u10 = cmulf(ep, m10);
        v1[q][0] = u00.x; v1[q][1] = u00.y; v1[q][2] = u10.x; v1[q][3] = u10.y;
    } else if (tid >= 64 && tid < 78) {  // layer-2 fused matrices
        int q = tid - 64, a = 70 + 3 * q;
        float t1 = sigmoid2pi(params[b * NP + a] + base[a]);
        float t2 = sigmoid2pi(params[b * NP + a + 1] + base[a + 1]);
        float t3 = sigmoid2pi(params[b * NP + a + 2] + base[a + 2]);
        float s1, c1, s2, c2, s3, c3;
        __sincosf(0.5f * t1, &s1, &c1);
        __sincosf(0.5f * t2, &s2, &c2);
        __sincosf(0.5f * t3, &s3, &c3);
        f2 m00 = make_float2(c2 * c1, s2 * s1);
        f2 m01 = make_float2(-s2 * c1, -c2 * s1);
        f2 m10 = make_float2(s2 * c1, -c2 * s1);
        f2 m11 = make_float2(c2 * c1, -s2 * s1);
        f2 em = make_float2(c3, -s3), ep = make_float2(c3, s3);
        f2 u00 = cmulf(em, m00), u01 = cmulf(em, m01);
        f2 u10 = cmulf(ep, m10), u11 = cmulf(ep, m11);
        g1[q][0] = u00.x; g1[q][1] = u00.y; g1[q][2] = u01.x; g1[q][3] = u01.y;
        g1[q][4] = u10.x; g1[q][5] = u10.y; g1[q][6] = u11.x; g1[q][7] = u11.y;
    } else if (tid >= 128 && tid < 184) { // CRX cos/sin in execution order
        int s = tid - 128;
        int layer = s / 28, k = s % 28;
        int aidx = layer * 70 + (k < 14 ? 42 + k : 56 + (k - 14));
        float th = sigmoid2pi(params[b * NP + aidx] + base[aidx]);
        float sh, ch;
        __sincosf(0.5f * th, &sh, &ch);
        csh[s][0] = ch; csh[s][1] = sh;
    }
    __syncthreads();

    // ------- initial state: product of layer-1 1q columns -------
    f2 F = make_float2(1.f, 0.f);
    #pragma unroll
    for (int q = 0; q < 10; ++q) {
        int bit = (tid >> (9 - q)) & 1;
        f2 v = make_float2(v1[q][2 * bit], v1[q][2 * bit + 1]);
        F = cmulf(F, v);
    }
    f2 st[16];
    {
        f2 t2a[2], t4a[4], t8a[8];
        #pragma unroll
        for (int a = 0; a < 2; ++a)
            t2a[a] = cmulf(F, make_float2(v1[10][2 * a], v1[10][2 * a + 1]));
        #pragma unroll
        for (int a = 0; a < 4; ++a)
            t4a[a] = cmulf(t2a[a >> 1], make_float2(v1[11][2 * (a & 1)], v1[11][2 * (a & 1) + 1]));
        #pragma unroll
        for (int a = 0; a < 8; ++a)
            t8a[a] = cmulf(t4a[a >> 1], make_float2(v1[12][2 * (a & 1)], v1[12][2 * (a & 1) + 1]));
        #pragma unroll
        for (int i = 0; i < 16; ++i)
            st[i] = cmulf(t8a[i >> 1], make_float2(v1[13][2 * (i & 1)], v1[13][2 * (i & 1) + 1]));
    }

    // ------- gate sequence -------
#define CRXF_(L, i, j) gatecrx<i, j>(st, ex, tid, csh[(L)*28 + (i)][0], csh[(L)*28 + (i)][1]);
#define CRXB_(L, i, j) gatecrx<i, j>(st, ex, tid, csh[(L)*28 + 27 - (i)][0], csh[(L)*28 + 27 - (i)][1]);
#define FWD_RING(L) \
    CRXF_(L,0,1) CRXF_(L,1,2) CRXF_(L,2,3) CRXF_(L,3,4) CRXF_(L,4,5) CRXF_(L,5,6) CRXF_(L,6,7) \
    CRXF_(L,7,8) CRXF_(L,8,9) CRXF_(L,9,10) CRXF_(L,10,11) CRXF_(L,11,12) CRXF_(L,12,13) CRXF_(L,13,0)
#define BWD_RING(L) \
    CRXB_(L,13,12) CRXB_(L,12,11) CRXB_(L,11,10) CRXB_(L,10,9) CRXB_(L,9,8) CRXB_(L,8,7) CRXB_(L,7,6) \
    CRXB_(L,6,5) CRXB_(L,5,4) CRXB_(L,4,3) CRXB_(L,3,2) CRXB_(L,2,1) CRXB_(L,1,0) CRXB_(L,0,13)
#define G1Q(q) gate1q<q>(st, ex, tid, g1[q]);

    // layer 1 (1q section folded into initial state)
    FWD_RING(0)
    BWD_RING(0)
    // layer 2
    G1Q(0) G1Q(1) G1Q(2) G1Q(3) G1Q(4) G1Q(5) G1Q(6)
    G1Q(7) G1Q(8) G1Q(9) G1Q(10) G1Q(11) G1Q(12) G1Q(13)
    FWD_RING(1)
    BWD_RING(1)

    // ------- dump state for wave-bit measurement wires -------
    __syncthreads();
    #pragma unroll
    for (int i = 0; i < 16; ++i) ex[i][tid] = st[i];
    __syncthreads();

#define MEAS(W) measure_wire<W>(st, ex, tid, red);
    MEAS(0) MEAS(1) MEAS(2) MEAS(3) MEAS(4) MEAS(5) MEAS(6)
    MEAS(7) MEAS(8) MEAS(9) MEAS(10) MEAS(11) MEAS(12) MEAS(13)

    __syncthreads();
    if (tid < 42) {
        int comp = tid / 14, w = tid % 14;
        float s = 0.f;
        #pragma unroll
        for (int k = 0; k < 16; ++k) s += red[w][k][comp];
        out[b * 42 + comp * 14 + w] = s;
    }
}

extern "C" void kernel_launch(void* const* d_in, const int* in_sizes, int n_in,
                              void* d_out, int out_size, void* d_ws, size_t ws_size,
                              hipStream_t stream) {
    const float* params = (const float*)d_in[0];   // [B, 140]
    const float* base   = (const float*)d_in[1];   // [140]
    float* out = (float*)d_out;                    // [B, 42]
    const int B = in_sizes[0] / NP;
    qfe_kernel<<<B, NT, 0, stream>>>(params, base, out);
}

// Round 4
// 110.912 us; speedup vs baseline: 4.1892x; 1.0019x over previous
//
#include <hip/hip_runtime.h>
#include <math.h>

#define NQ 14
#define NP 140
#define NT 1024

typedef float2 f2;

__device__ __forceinline__ float sigmoid2pi(float x) {
    return 6.28318530717958647692f / (1.0f + __expf(-x));
}

__device__ __forceinline__ f2 cmulf(f2 a, f2 b) {
    return make_float2(a.x * b.x - a.y * b.y, a.x * b.y + a.y * b.x);
}

// ca*m + cb*o (complex)
__device__ __forceinline__ f2 comb(f2 ca, f2 m, f2 cb, f2 o) {
    return make_float2(ca.x * m.x - ca.y * m.y + cb.x * o.x - cb.y * o.y,
                       ca.x * m.y + ca.y * m.x + cb.x * o.y + cb.y * o.x);
}

// RX half: n = ch*m - i*sh*o
__device__ __forceinline__ f2 rxmix(float ch, float sh, f2 m, f2 o) {
    return make_float2(ch * m.x + sh * o.y, ch * m.y - sh * o.x);
}

// ---------------- fused RZ*RY*RX single-qubit gate ----------------
template<int Q>
__device__ __forceinline__ void gate1q(f2 (&st)[16], f2 (*ex)[NT], int tid, const float* g) {
    f2 u00 = make_float2(g[0], g[1]), u01 = make_float2(g[2], g[3]);
    f2 u10 = make_float2(g[4], g[5]), u11 = make_float2(g[6], g[7]);
    constexpr int B = 13 - Q;
    if constexpr (B < 4) {                       // register-local pairs
        constexpr int M = 1 << B;
        #pragma unroll
        for (int p = 0; p < 8; ++p) {
            int i0 = ((p >> B) << (B + 1)) | (p & (M - 1));
            int i1 = i0 | M;
            f2 a0 = st[i0], a1 = st[i1];
            st[i0] = comb(u00, a0, u01, a1);
            st[i1] = comb(u10, a0, u11, a1);
        }
    } else if constexpr (B < 10) {               // lane-bit: shuffle exchange
        constexpr int LM = 1 << (B - 4);
        int bit = (tid >> (B - 4)) & 1;
        f2 ca = bit ? u11 : u00;
        f2 cb = bit ? u10 : u01;
        #pragma unroll
        for (int i = 0; i < 16; ++i) {
            f2 o;
            o.x = __shfl_xor(st[i].x, LM);
            o.y = __shfl_xor(st[i].y, LM);
            st[i] = comb(ca, st[i], cb, o);
        }
    } else {                                     // wave-bit: LDS exchange
        constexpr int TM = 1 << (B - 4);
        int bit = (tid >> (B - 4)) & 1;
        f2 ca = bit ? u11 : u00;
        f2 cb = bit ? u10 : u01;
        int ptid = tid ^ TM;
        __syncthreads();
        #pragma unroll
        for (int i = 0; i < 16; ++i) ex[i][tid] = st[i];
        __syncthreads();
        #pragma unroll
        for (int i = 0; i < 16; ++i) {
            f2 o = ex[i][ptid];
            st[i] = comb(ca, st[i], cb, o);
        }
    }
}

// ---------------- controlled-RX ----------------
template<int C, int T>
__device__ __forceinline__ void gatecrx(f2 (&st)[16], f2 (*ex)[NT], int tid, float ch, float sh) {
    constexpr int TB = 13 - T, CB = 13 - C;
    if constexpr (TB < 4) {                      // target register-local
        constexpr int M = 1 << TB;
        if constexpr (CB < 4) {                  // ctrl local: compile-time subset
            #pragma unroll
            for (int p = 0; p < 8; ++p) {
                int i0 = ((p >> TB) << (TB + 1)) | (p & (M - 1));
                int i1 = i0 | M;
                if ((i0 >> CB) & 1) {
                    f2 a0 = st[i0], a1 = st[i1];
                    st[i0] = rxmix(ch, sh, a0, a1);
                    st[i1] = rxmix(ch, sh, a1, a0);
                }
            }
        } else {                                 // ctrl lane/wave: uniform predicate
            bool sel = (tid >> (CB - 4)) & 1;
            if (sel) {
                #pragma unroll
                for (int p = 0; p < 8; ++p) {
                    int i0 = ((p >> TB) << (TB + 1)) | (p & (M - 1));
                    int i1 = i0 | M;
                    f2 a0 = st[i0], a1 = st[i1];
                    st[i0] = rxmix(ch, sh, a0, a1);
                    st[i1] = rxmix(ch, sh, a1, a0);
                }
            }
        }
    } else if constexpr (TB < 10) {              // target lane-bit
        constexpr int LM = 1 << (TB - 4);
        if constexpr (CB < 4) {                  // ctrl local: shuffle only needed amps
            #pragma unroll
            for (int i = 0; i < 16; ++i) {
                if ((i >> CB) & 1) {
                    f2 o;
                    o.x = __shfl_xor(st[i].x, LM);
                    o.y = __shfl_xor(st[i].y, LM);
                    st[i] = rxmix(ch, sh, st[i], o);
                }
            }
        } else if constexpr (CB >= 10) {         // ctrl wave: wave-uniform branch
            bool sel = (tid >> (CB - 4)) & 1;
            if (sel) {
                #pragma unroll
                for (int i = 0; i < 16; ++i) {
                    f2 o;
                    o.x = __shfl_xor(st[i].x, LM);
                    o.y = __shfl_xor(st[i].y, LM);
                    st[i] = rxmix(ch, sh, st[i], o);
                }
            }
        } else {                                 // ctrl lane: divergent -> select
            bool sel = (tid >> (CB - 4)) & 1;
            #pragma unroll
            for (int i = 0; i < 16; ++i) {
                f2 o;
                o.x = __shfl_xor(st[i].x, LM);
                o.y = __shfl_xor(st[i].y, LM);
                f2 n = rxmix(ch, sh, st[i], o);
                st[i] = sel ? n : st[i];
            }
        }
    } else {                                     // target wave-bit: LDS exchange
        constexpr int TM = 1 << (TB - 4);
        int ptid = tid ^ TM;
        bool act = true;
        if constexpr (CB >= 4) act = (tid >> (CB - 4)) & 1;
        __syncthreads();
        if (act) {
            #pragma unroll
            for (int i = 0; i < 16; ++i) {
                if constexpr (CB < 4) { if (!((i >> CB) & 1)) continue; }
                ex[i][tid] = st[i];
            }
        }
        __syncthreads();
        if (act) {
            #pragma unroll
            for (int i = 0; i < 16; ++i) {
                if constexpr (CB < 4) { if (!((i >> CB) & 1)) continue; }
                f2 o = ex[i][ptid];
                st[i] = rxmix(ch, sh, st[i], o);
            }
        }
    }
}

// ---------------- measurement of one wire ----------------
template<int W>
__device__ __forceinline__ void measure_wire(const f2 (&st)[16], f2 (*ex)[NT], int tid,
                                             float red[14][16][3]) {
    constexpr int B = 13 - W;
    float sx = 0.f, sy = 0.f, sz = 0.f;
    if constexpr (B < 4) {                       // local pairs
        constexpr int M = 1 << B;
        #pragma unroll
        for (int p = 0; p < 8; ++p) {
            int i0 = ((p >> B) << (B + 1)) | (p & (M - 1));
            int i1 = i0 | M;
            f2 a0 = st[i0], a1 = st[i1];
            sx += a0.x * a1.x + a0.y * a1.y;
            sy += a0.x * a1.y - a0.y * a1.x;
            sz += (a0.x * a0.x + a0.y * a0.y) - (a1.x * a1.x + a1.y * a1.y);
        }
        sx *= 2.f; sy *= 2.f;                    // local pairs counted once
    } else {                                     // both-sides accumulation
        int bit = (tid >> (B - 4)) & 1;
        float sg = bit ? -1.f : 1.f;
        #pragma unroll
        for (int i = 0; i < 16; ++i) {
            f2 m = st[i], o;
            if constexpr (B < 10) {
                o.x = __shfl_xor(m.x, 1 << (B - 4));
                o.y = __shfl_xor(m.y, 1 << (B - 4));
            } else {
                o = ex[i][tid ^ (1 << (B - 4))];
            }
            sx += m.x * o.x + m.y * o.y;
            sy += sg * (m.x * o.y - m.y * o.x);
            sz += sg * (m.x * m.x + m.y * m.y);
        }
    }
    // wave-level reduce
    #pragma unroll
    for (int off = 32; off > 0; off >>= 1) {
        sx += __shfl_down(sx, off);
        sy += __shfl_down(sy, off);
        sz += __shfl_down(sz, off);
    }
    if ((tid & 63) == 0) {
        int wv = tid >> 6;
        red[W][wv][0] = sx; red[W][wv][1] = sy; red[W][wv][2] = sz;
    }
}

__global__ __launch_bounds__(NT)
__attribute__((amdgpu_waves_per_eu(4, 4)))   // pin 4 waves/EU (1 block/CU, LDS-forced) -> 128-VGPR budget
void qfe_kernel(const float* __restrict__ params,
                const float* __restrict__ base,
                float* __restrict__ out)
{
    __shared__ f2 ex[16][NT];            // 128 KB exchange buffer
    __shared__ float v1[14][4];          // layer-1 1q columns (u00, u10)
    __shared__ float g1[14][8];          // layer-2 fused 1q matrices
    __shared__ float csh[56][2];         // CRX (cos, sin) half-angle, exec order
    __shared__ float red[14][16][3];     // per-wave measurement partials

    const int b = blockIdx.x;
    const int tid = threadIdx.x;

    // ------- precompute all gate data (divergent, one-time) -------
    if (tid < 14) {                      // layer-1 columns
        int q = tid, a = 3 * q;
        float t1 = sigmoid2pi(params[b * NP + a] + base[a]);
        float t2 = sigmoid2pi(params[b * NP + a + 1] + base[a + 1]);
        float t3 = sigmoid2pi(params[b * NP + a + 2] + base[a + 2]);
        float s1, c1, s2, c2, s3, c3;
        __sincosf(0.5f * t1, &s1, &c1);
        __sincosf(0.5f * t2, &s2, &c2);
        __sincosf(0.5f * t3, &s3, &c3);
        f2 m00 = make_float2(c2 * c1, s2 * s1);
        f2 m10 = make_float2(s2 * c1, -c2 * s1);
        f2 em = make_float2(c3, -s3), ep = make_float2(c3, s3);
        f2 u00 = cmulf(em, m00), u10 = cmulf(ep, m10);
        v1[q][0] = u00.x; v1[q][1] = u00.y; v1[q][2] = u10.x; v1[q][3] = u10.y;
    } else if (tid >= 64 && tid < 78) {  // layer-2 fused matrices
        int q = tid - 64, a = 70 + 3 * q;
        float t1 = sigmoid2pi(params[b * NP + a] + base[a]);
        float t2 = sigmoid2pi(params[b * NP + a + 1] + base[a + 1]);
        float t3 = sigmoid2pi(params[b * NP + a + 2] + base[a + 2]);
        float s1, c1, s2, c2, s3, c3;
        __sincosf(0.5f * t1, &s1, &c1);
        __sincosf(0.5f * t2, &s2, &c2);
        __sincosf(0.5f * t3, &s3, &c3);
        f2 m00 = make_float2(c2 * c1, s2 * s1);
        f2 m01 = make_float2(-s2 * c1, -c2 * s1);
        f2 m10 = make_float2(s2 * c1, -c2 * s1);
        f2 m11 = make_float2(c2 * c1, -s2 * s1);
        f2 em = make_float2(c3, -s3), ep = make_float2(c3, s3);
        f2 u00 = cmulf(em, m00), u01 = cmulf(em, m01);
        f2 u10 = cmulf(ep, m10), u11 = cmulf(ep, m11);
        g1[q][0] = u00.x; g1[q][1] = u00.y; g1[q][2] = u01.x; g1[q][3] = u01.y;
        g1[q][4] = u10.x; g1[q][5] = u10.y; g1[q][6] = u11.x; g1[q][7] = u11.y;
    } else if (tid >= 128 && tid < 184) { // CRX cos/sin in execution order
        int s = tid - 128;
        int layer = s / 28, k = s % 28;
        int aidx = layer * 70 + (k < 14 ? 42 + k : 56 + (k - 14));
        float th = sigmoid2pi(params[b * NP + aidx] + base[aidx]);
        float sh, ch;
        __sincosf(0.5f * th, &sh, &ch);
        csh[s][0] = ch; csh[s][1] = sh;
    }
    __syncthreads();

    // ------- initial state: product of layer-1 1q columns -------
    f2 F = make_float2(1.f, 0.f);
    #pragma unroll
    for (int q = 0; q < 10; ++q) {
        int bit = (tid >> (9 - q)) & 1;
        f2 v = make_float2(v1[q][2 * bit], v1[q][2 * bit + 1]);
        F = cmulf(F, v);
    }
    f2 st[16];
    {
        f2 t2a[2], t4a[4], t8a[8];
        #pragma unroll
        for (int a = 0; a < 2; ++a)
            t2a[a] = cmulf(F, make_float2(v1[10][2 * a], v1[10][2 * a + 1]));
        #pragma unroll
        for (int a = 0; a < 4; ++a)
            t4a[a] = cmulf(t2a[a >> 1], make_float2(v1[11][2 * (a & 1)], v1[11][2 * (a & 1) + 1]));
        #pragma unroll
        for (int a = 0; a < 8; ++a)
            t8a[a] = cmulf(t4a[a >> 1], make_float2(v1[12][2 * (a & 1)], v1[12][2 * (a & 1) + 1]));
        #pragma unroll
        for (int i = 0; i < 16; ++i)
            st[i] = cmulf(t8a[i >> 1], make_float2(v1[13][2 * (i & 1)], v1[13][2 * (i & 1) + 1]));
    }

    // ------- gate sequence -------
#define CRXF_(L, i, j) gatecrx<i, j>(st, ex, tid, csh[(L)*28 + (i)][0], csh[(L)*28 + (i)][1]);
#define CRXB_(L, i, j) gatecrx<i, j>(st, ex, tid, csh[(L)*28 + 27 - (i)][0], csh[(L)*28 + 27 - (i)][1]);
#define FWD_RING(L) \
    CRXF_(L,0,1) CRXF_(L,1,2) CRXF_(L,2,3) CRXF_(L,3,4) CRXF_(L,4,5) CRXF_(L,5,6) CRXF_(L,6,7) \
    CRXF_(L,7,8) CRXF_(L,8,9) CRXF_(L,9,10) CRXF_(L,10,11) CRXF_(L,11,12) CRXF_(L,12,13) CRXF_(L,13,0)
#define BWD_RING(L) \
    CRXB_(L,13,12) CRXB_(L,12,11) CRXB_(L,11,10) CRXB_(L,10,9) CRXB_(L,9,8) CRXB_(L,8,7) CRXB_(L,7,6) \
    CRXB_(L,6,5) CRXB_(L,5,4) CRXB_(L,4,3) CRXB_(L,3,2) CRXB_(L,2,1) CRXB_(L,1,0) CRXB_(L,0,13)
#define G1Q(q) gate1q<q>(st, ex, tid, g1[q]);

    // layer 1 (1q section folded into initial state)
    FWD_RING(0)
    BWD_RING(0)
    // layer 2
    G1Q(0) G1Q(1) G1Q(2) G1Q(3) G1Q(4) G1Q(5) G1Q(6)
    G1Q(7) G1Q(8) G1Q(9) G1Q(10) G1Q(11) G1Q(12) G1Q(13)
    FWD_RING(1)
    BWD_RING(1)

    // ------- dump state for wave-bit measurement wires -------
    __syncthreads();
    #pragma unroll
    for (int i = 0; i < 16; ++i) ex[i][tid] = st[i];
    __syncthreads();

#define MEAS(W) measure_wire<W>(st, ex, tid, red);
    MEAS(0) MEAS(1) MEAS(2) MEAS(3) MEAS(4) MEAS(5) MEAS(6)
    MEAS(7) MEAS(8) MEAS(9) MEAS(10) MEAS(11) MEAS(12) MEAS(13)

    __syncthreads();
    if (tid < 42) {
        int comp = tid / 14, w = tid % 14;
        float s = 0.f;
        #pragma unroll
        for (int k = 0; k < 16; ++k) s += red[w][k][comp];
        out[b * 42 + comp * 14 + w] = s;
    }
}

extern "C" void kernel_launch(void* const* d_in, const int* in_sizes, int n_in,
                              void* d_out, int out_size, void* d_ws, size_t ws_size,
                              hipStream_t stream) {
    const float* params = (const float*)d_in[0];   // [B, 140]
    const float* base   = (const float*)d_in[1];   // [140]
    float* out = (float*)d_out;                    // [B, 42]
    const int B = in_sizes[0] / NP;
    qfe_kernel<<<B, NT, 0, stream>>>(params, base, out);
}